// Round 1
// 2483.052 us; speedup vs baseline: 1.0856x; 1.0856x over previous
//
#include <hip/hip_runtime.h>
#include <cstdint>
#include <cstddef>

// Problem constants
#define NB    64      // batch
#define NS    4096    // seq len (x_logits width)
#define NH    1024    // hidden
#define NOPSN 8
#define NSTEP 10

#define GRID  256
#define TPB   1024    // 16 waves/block -> 4 waves/SIMD at 1 block/CU

// Workspace layout (float offsets). Total ~8.9 MB.
#define OFF_H    0u        // h        [64][1024]
#define OFF_HN   65536u    // h_n      [64][1024]
#define OFF_PX   131072u   // px partials [4][64][4096]  (x_logits split-K)
#define OFF_PC   1179648u  // pc partials [16][64][1024] (W_res split-K)
#define OFF_CTRL 2228224u  // int ctrl area
// ctrl ints: [0]=magic [1]=barrier cnt [2..11]=stopcnt[t] [16..26]=done[t] [32..95]=ptr[b]
#define MAGIC    0x1357A5E5

__device__ __forceinline__ float bcastf(float v, int l) {
  return __int_as_float(__builtin_amdgcn_readlane(__float_as_int(v), l));
}

// Device-scope grid barrier. Safe: 256 blocks, __launch_bounds__(1024,4)
// guarantees 1 block/CU schedulable on 256 CUs -> all blocks resident.
__device__ __forceinline__ void gridbar(int* cnt, int target) {
  __syncthreads();
  if (threadIdx.x == 0) {
    __threadfence();  // release prior writes (device scope)
    __hip_atomic_fetch_add(cnt, 1, __ATOMIC_RELAXED, __HIP_MEMORY_SCOPE_AGENT);
    while (__hip_atomic_load(cnt, __ATOMIC_RELAXED, __HIP_MEMORY_SCOPE_AGENT) < target)
      __builtin_amdgcn_s_sleep(1);
    __threadfence();  // acquire
  }
  __syncthreads();
}

__global__ void __launch_bounds__(TPB, 4)
sys1_kernel(const float* __restrict__ s2a,  const float* __restrict__ Wres,
            const float* __restrict__ bres, const float* __restrict__ Wop,
            const float* __restrict__ bop,  const float* __restrict__ Wx,
            const float* __restrict__ bx,   const float* __restrict__ noise,
            float* __restrict__ out,        float* __restrict__ wsf)
{
  __shared__ float smem[16384];   // 64 KB: weight-slice stage (B:64KB, C:32KB), R scratch

  float* __restrict__ h  = wsf + OFF_H;
  float* __restrict__ hn = wsf + OFF_HN;
  float* __restrict__ px = wsf + OFF_PX;
  float* __restrict__ pc = wsf + OFF_PC;
  int* ctrl = (int*)(wsf + OFF_CTRL);
  int* cnt  = ctrl + 1;

  const int tid = threadIdx.x;
  const int blk = blockIdx.x;

  // ---- bootstrap: block 0 inits ctrl (ws is poisoned every launch) ----
  if (blk == 0 && tid == 0) {
    #pragma unroll
    for (int i = 1; i < 32; ++i) ctrl[i] = 0;
    __threadfence();
    __hip_atomic_store(&ctrl[0], (int)MAGIC, __ATOMIC_RELEASE, __HIP_MEMORY_SCOPE_AGENT);
  }
  if (tid == 0) {
    while (__hip_atomic_load(&ctrl[0], __ATOMIC_RELAXED, __HIP_MEMORY_SCOPE_AGENT) != (int)MAGIC)
      __builtin_amdgcn_s_sleep(1);
    __threadfence();
  }
  __syncthreads();

  // ---- init: h = 0, h_n = 0 + 0.01*noise[0] ----
  if (blk < NB) {
    int idx = blk * TPB + tid;          // 64 blocks x 1024 = 65536
    h[idx]  = 0.f;
    hn[idx] = 0.01f * noise[idx];
  }
  int ep = 0;
  gridbar(cnt, ++ep * GRID);

  const int lane = tid & 63;

  for (int t = 0; t < NSTEP; ++t) {

    // =========== Phase B: x_logits partials ===========
    // block = (sg 0..63, ksl 0..3): owns s0..s0+63 cols, k0..k0+255 of K.
    // Stage Wx[k0:k0+256][s0:s0+64] in LDS (float2-packed over k pairs).
    // wave w (0..15) = batch quarter bh: b in {4w..4w+3}, acc[4].
    {
      const int sg = blk >> 2;
      const int ksl = blk & 3;
      const int s0 = sg << 6;
      const int k0 = ksl << 8;
      float2* wl2 = (float2*)smem;               // [128 kp][64 s]
      #pragma unroll
      for (int i = 0; i < 8; ++i) {
        int id = i * TPB + tid;                  // 0..8191
        int kp = id >> 6, ss = id & 63;
        const float* wp = Wx + (size_t)(k0 + 2 * kp) * NS + (s0 + ss);
        wl2[id] = make_float2(wp[0], wp[NS]);
      }
      __syncthreads();

      const int bbase = (tid >> 6) << 2;
      const int lk = lane & 31;
      const float* hb = hn + (size_t)bbase * NH + k0 + lk;
      float acc0 = 0.f, acc1 = 0.f, acc2 = 0.f, acc3 = 0.f;
      float hv0 = hb[0], hv1 = hb[NH], hv2 = hb[2 * NH], hv3 = hb[3 * NH];

      #pragma unroll 1
      for (int kc = 0; kc < 256; kc += 32) {
        float w[32];
        #pragma unroll
        for (int kp2 = 0; kp2 < 16; ++kp2) {
          float2 f = wl2[((kc >> 1) + kp2) * 64 + lane];
          w[2 * kp2] = f.x; w[2 * kp2 + 1] = f.y;
        }
        float p0, p1, p2, p3;                    // prefetch next chunk's h
        if (kc + 32 < 256) {
          const float* hbn = hb + kc + 32;
          p0 = hbn[0]; p1 = hbn[NH]; p2 = hbn[2 * NH]; p3 = hbn[3 * NH];
        }
        #pragma unroll
        for (int kk = 0; kk < 32; ++kk) {
          float wv_ = w[kk];
          acc0 += bcastf(hv0, kk) * wv_;
          acc1 += bcastf(hv1, kk) * wv_;
          acc2 += bcastf(hv2, kk) * wv_;
          acc3 += bcastf(hv3, kk) * wv_;
        }
        if (kc + 32 < 256) { hv0 = p0; hv1 = p1; hv2 = p2; hv3 = p3; }
      }
      float* po = px + ((size_t)ksl * NB + bbase) * NS + s0 + lane;
      po[0] = acc0; po[(size_t)NS] = acc1;
      po[(size_t)2 * NS] = acc2; po[(size_t)3 * NS] = acc3;
    }
    gridbar(cnt, ++ep * GRID);

    // =========== Phase R: per-b argmax over S + op logits (blocks 0..63) ===========
    if (blk < NB) {
      const int b = blk;
      float bestv = -3.402823466e+38f; int besti = 0;
      #pragma unroll
      for (int so = 0; so < NS; so += TPB) {     // 4 iterations
        int s = so + tid;
        float v = bx[s]
                + px[(size_t)(0 * NB + b) * NS + s]
                + px[(size_t)(1 * NB + b) * NS + s]
                + px[(size_t)(2 * NB + b) * NS + s]
                + px[(size_t)(3 * NB + b) * NS + s];
        if (v > bestv) { bestv = v; besti = s; }          // ascending s -> first-max
      }
      // wave-level argmax reduce (prefer smaller index on equal)
      #pragma unroll
      for (int off = 32; off; off >>= 1) {
        float ov = __shfl_down(bestv, off);
        int   oi = __shfl_down(besti, off);
        if (ov > bestv || (ov == bestv && oi < besti)) { bestv = ov; besti = oi; }
      }
      // op logits: hn[b] . W_op  (8 outputs), K == TPB exactly
      float op[8];
      {
        const float hvv = hn[(size_t)b * NH + tid];
        const float* wr = Wop + (size_t)tid * NOPSN;
        #pragma unroll
        for (int o = 0; o < 8; ++o) op[o] = hvv * wr[o];
      }
      #pragma unroll
      for (int off = 32; off; off >>= 1) {
        #pragma unroll
        for (int o = 0; o < 8; ++o) op[o] += __shfl_down(op[o], off);
      }
      // cross-wave combine via LDS (16 waves)
      float* rv  = smem;                 // [16]
      int*   rix = (int*)(smem + 16);    // [16]
      float* rop = smem + 32;            // [16][8]
      if (lane == 0) {
        int w = tid >> 6;
        rv[w] = bestv; rix[w] = besti;
        #pragma unroll
        for (int o = 0; o < 8; ++o) rop[w * 8 + o] = op[o];
      }
      __syncthreads();
      if (tid == 0) {
        float bv2 = rv[0]; int bi2 = rix[0];
        for (int w = 1; w < 16; ++w) {
          float ov = rv[w]; int oi = rix[w];
          if (ov > bv2 || (ov == bv2 && oi < bi2)) { bv2 = ov; bi2 = oi; }
        }
        int ip = bi2 > NS - 1 ? NS - 1 : bi2;
        ctrl[32 + b] = ip;
        float bv = 0.f; int bo = 0;
        {
          float s0v = 0.f;
          for (int w = 0; w < 16; ++w) s0v += rop[w * 8 + 0];
          bv = s0v + bop[0];
        }
        for (int o = 1; o < 8; ++o) {
          float sv = 0.f;
          for (int w = 0; w < 16; ++w) sv += rop[w * 8 + o];
          float v = sv + bop[o];
          if (v > bv) { bv = v; bo = o; }          // strict > : first-max
        }
        if (bo == 0) atomicAdd(&ctrl[2 + t], 1);
      }
    }
    gridbar(cnt, ++ep * GRID);

    // =========== Phase C: h_new partials = concat(h_n, s2a[b][ptr[b]]) @ W_res ===========
    // block = (jg 0..15, kslc 0..15): owns j0..j0+63 cols, k0..k0+127 of K=2048.
    // Stage Wres[k0:k0+128][j0:j0+64] in LDS. wave w = batch 1/16th: b in {4w..4w+3}.
    {
      const int jg = blk & 15, kslc = blk >> 4;
      const int j0 = jg << 6;
      const int k0 = kslc << 7;
      float2* wl2 = (float2*)smem;               // [64 kp][64 j]
      #pragma unroll
      for (int i = 0; i < 4; ++i) {
        int id = i * TPB + tid;                  // 0..4095
        int kp = id >> 6, jj = id & 63;
        const float* wp = Wres + (size_t)(k0 + 2 * kp) * NH + (j0 + jj);
        wl2[id] = make_float2(wp[0], wp[NH]);
      }
      __syncthreads();

      const int bbase = (tid >> 6) << 2;
      const int lk = lane & 31;
      const float *sp0, *sp1, *sp2, *sp3;        // per-b source (block-uniform branch)
      if (kslc < 8) {
        const float* hbb = hn + (size_t)bbase * NH + k0 + lk;
        sp0 = hbb; sp1 = hbb + NH; sp2 = hbb + 2 * NH; sp3 = hbb + 3 * NH;
      } else {
        sp0 = s2a + ((size_t)(bbase + 0) * NS + ctrl[32 + bbase + 0]) * NH + (k0 - NH) + lk;
        sp1 = s2a + ((size_t)(bbase + 1) * NS + ctrl[32 + bbase + 1]) * NH + (k0 - NH) + lk;
        sp2 = s2a + ((size_t)(bbase + 2) * NS + ctrl[32 + bbase + 2]) * NH + (k0 - NH) + lk;
        sp3 = s2a + ((size_t)(bbase + 3) * NS + ctrl[32 + bbase + 3]) * NH + (k0 - NH) + lk;
      }
      float acc0 = 0.f, acc1 = 0.f, acc2 = 0.f, acc3 = 0.f;
      float hv0 = sp0[0], hv1 = sp1[0], hv2 = sp2[0], hv3 = sp3[0];

      #pragma unroll 1
      for (int kc = 0; kc < 128; kc += 32) {
        float w[32];
        #pragma unroll
        for (int kp2 = 0; kp2 < 16; ++kp2) {
          float2 f = wl2[((kc >> 1) + kp2) * 64 + lane];
          w[2 * kp2] = f.x; w[2 * kp2 + 1] = f.y;
        }
        float p0, p1, p2, p3;
        if (kc + 32 < 128) {
          p0 = sp0[kc + 32]; p1 = sp1[kc + 32]; p2 = sp2[kc + 32]; p3 = sp3[kc + 32];
        }
        #pragma unroll
        for (int kk = 0; kk < 32; ++kk) {
          float wv_ = w[kk];
          acc0 += bcastf(hv0, kk) * wv_;
          acc1 += bcastf(hv1, kk) * wv_;
          acc2 += bcastf(hv2, kk) * wv_;
          acc3 += bcastf(hv3, kk) * wv_;
        }
        if (kc + 32 < 128) { hv0 = p0; hv1 = p1; hv2 = p2; hv3 = p3; }
      }
      float* po = pc + ((size_t)kslc * NB + bbase) * NH + j0 + lane;
      po[0] = acc0; po[(size_t)NH] = acc1;
      po[(size_t)2 * NH] = acc2; po[(size_t)3 * NH] = acc3;
    }
    gridbar(cnt, ++ep * GRID);

    // =========== Phase D: reduce partials, done/freeze logic, next h_n ===========
    if (blk < NB) {
      const int idx = blk * TPB + tid;       // 0..65535
      const int b = idx >> 10, j = idx & 1023;
      float v = bres[j];
      #pragma unroll
      for (int sl = 0; sl < 16; ++sl) v += pc[(size_t)(sl * NB + b) * NH + j];
      int done = ctrl[16 + t];
      float hcur = h[idx];
      float hout = done ? hcur : v;
      h[idx] = hout;
      if (t < NSTEP - 1) hn[idx] = hout + 0.01f * noise[(size_t)(t + 1) * (NB * NH) + idx];
      else out[idx] = hout;
      if (idx == 0) {
        int stop = ctrl[2 + t];
        ctrl[16 + t + 1] = done | (stop == NB ? 1 : 0);
      }
    }
    if (t < NSTEP - 1) gridbar(cnt, ++ep * GRID);
  }
}

extern "C" void kernel_launch(void* const* d_in, const int* in_sizes, int n_in,
                              void* d_out, int out_size, void* d_ws, size_t ws_size,
                              hipStream_t stream) {
  const float* s2a   = (const float*)d_in[0];
  const float* Wres  = (const float*)d_in[1];
  const float* bres  = (const float*)d_in[2];
  const float* Wop   = (const float*)d_in[3];
  const float* bop   = (const float*)d_in[4];
  const float* Wx    = (const float*)d_in[5];
  const float* bx    = (const float*)d_in[6];
  const float* noise = (const float*)d_in[7];
  float* outp = (float*)d_out;
  float* wsf  = (float*)d_ws;   // needs ~8.9 MB
  hipLaunchKernelGGL(sys1_kernel, dim3(GRID), dim3(TPB), 0, stream,
                     s2a, Wres, bres, Wop, bop, Wx, bx, noise, outp, wsf);
}

// Round 2
// 2428.074 us; speedup vs baseline: 1.1102x; 1.0226x over previous
//
#include <hip/hip_runtime.h>
#include <cstdint>
#include <cstddef>

// Problem constants
#define NB    64      // batch
#define NS    4096    // seq len
#define NH    1024    // hidden
#define NOPSN 8
#define NSTEP 10

#define GRID  256
#define TPB   1024    // 16 waves/block, 1 block/CU -> 4 waves/SIMD

// Workspace layout (float offsets). Total ~1.2 MB.
#define OFF_HN   0u        // hn  [64][1024] row-major
#define OFF_HNT  65536u    // hnT [1024][64] transposed
#define OFF_H    131072u   // h   [64][1024]
#define OFF_CAND 196608u   // cand [64][256] float2 (val, idx-as-float)
#define OFF_OPP  229376u   // oppart [10][16 jg][64 b][8 o]
#define OFF_CTRL 311296u   // int ctrl: [0]=magic [1]=barrier cnt [2..11]=stopcnt[t]
#define MAGIC    0x1357A5E5

typedef float f4v  __attribute__((ext_vector_type(4)));
typedef float f16v __attribute__((ext_vector_type(16)));

__device__ __forceinline__ float bcastf(float v, int l) {
  return __int_as_float(__builtin_amdgcn_readlane(__float_as_int(v), l));
}

// Device-scope grid barrier. 256 blocks x (1024 thr, 64KB LDS, <=128 VGPR)
// -> 1 block/CU on 256 CUs, all resident.
__device__ __forceinline__ void gridbar(int* cnt, int target) {
  __syncthreads();
  if (threadIdx.x == 0) {
    __threadfence();  // release (device scope)
    __hip_atomic_fetch_add(cnt, 1, __ATOMIC_RELAXED, __HIP_MEMORY_SCOPE_AGENT);
    while (__hip_atomic_load(cnt, __ATOMIC_RELAXED, __HIP_MEMORY_SCOPE_AGENT) < target)
      __builtin_amdgcn_s_sleep(1);
    __threadfence();  // acquire
  }
  __syncthreads();
}

__global__ void __launch_bounds__(TPB, 4)
sys1_kernel(const float* __restrict__ s2a,  const float* __restrict__ Wres,
            const float* __restrict__ bres, const float* __restrict__ Wop,
            const float* __restrict__ bop,  const float* __restrict__ Wx,
            const float* __restrict__ bx,   const float* __restrict__ noise,
            float* __restrict__ out,        float* __restrict__ wsf)
{
  __shared__ float smem[16384];   // 64 KB: double-buffered stages + reductions

  float* __restrict__ hn  = wsf + OFF_HN;
  float* __restrict__ hnT = wsf + OFF_HNT;
  float* __restrict__ h   = wsf + OFF_H;
  float* __restrict__ opp = wsf + OFF_OPP;
  int* ctrl = (int*)(wsf + OFF_CTRL);
  int* cnt  = ctrl + 1;

  const int tid = threadIdx.x;
  const int blk = blockIdx.x;

  // ---- bootstrap: block 0 inits ctrl (ws is poisoned every launch) ----
  if (blk == 0 && tid == 0) {
    #pragma unroll
    for (int i = 1; i < 32; ++i) ctrl[i] = 0;
    __threadfence();
    __hip_atomic_store(&ctrl[0], (int)MAGIC, __ATOMIC_RELEASE, __HIP_MEMORY_SCOPE_AGENT);
  }
  if (tid == 0) {
    while (__hip_atomic_load(&ctrl[0], __ATOMIC_RELAXED, __HIP_MEMORY_SCOPE_AGENT) != (int)MAGIC)
      __builtin_amdgcn_s_sleep(1);
    __threadfence();
  }
  __syncthreads();

  const int lane = tid & 63;
  const int wv   = __builtin_amdgcn_readfirstlane(tid >> 6);   // wave 0..15

  // ---- INIT: hn(0) = 0.01*noise[0], hnT(0), h=0, oppart[0] ----
  {
    const int jg = blk & 15, bg = blk >> 4;
    if (tid < 256) {
      const int bsel = tid >> 6, jloc = tid & 63;
      const int b = bg * 4 + bsel, j = jg * 64 + jloc;
      float hv = 0.01f * noise[(size_t)b * NH + j];
      hn[(size_t)b * NH + j]  = hv;
      hnT[(size_t)j * NB + b] = hv;
      h[(size_t)b * NH + j]   = 0.f;
      const float* wr = Wop + (size_t)j * NOPSN;
      float opo[8];
      #pragma unroll
      for (int o = 0; o < 8; ++o) opo[o] = hv * wr[o];
      #pragma unroll
      for (int off = 1; off <= 32; off <<= 1) {
        #pragma unroll
        for (int o = 0; o < 8; ++o) opo[o] += __shfl_xor(opo[o], off);
      }
      if (lane == 0) {
        float* od = opp + ((size_t)0 * 16 + jg) * 512 + (size_t)b * 8;
        #pragma unroll
        for (int o = 0; o < 8; ++o) od[o] = opo[o];
      }
    }
  }
  int ep = 0;
  gridbar(cnt, ++ep * GRID);

  for (int st = 0; st < NSTEP; ++st) {

    // ================= PHASE A =================
    // Each block: x_logits[16 s cols][64 b], full K=1024. lane = b.
    // Weights via wave-uniform 64B scalar loads (1 VALU instr/MAC).
    {
      const int s0 = blk << 4;

      auto stageA = [&](int c, int sel) {
        const f4v* src = (const f4v*)(hnT + (size_t)c * 8192);
        f4v a = src[tid * 2], b2 = src[tid * 2 + 1];
        f4v* dst = (f4v*)(smem + sel * 8192);
        dst[tid * 2] = a; dst[tid * 2 + 1] = b2;
      };

      stageA(0, 0);

      // op-argmax for step st (blocks 0..63), overlapped with staging
      if (blk < NB && tid < 64) {
        const float* ob = opp + (size_t)st * 8192 + (size_t)blk * 8;
        const int o = lane & 7, jgb = lane >> 3;              // jgb 0..7
        float v = ob[(size_t)jgb * 512 + o] + ob[(size_t)(jgb + 8) * 512 + o];
        v += __shfl_xor(v, 8);
        v += __shfl_xor(v, 16);
        v += __shfl_xor(v, 32);
        v += bop[o];
        float bv = bcastf(v, 0); int bo = 0;
        #pragma unroll
        for (int oo = 1; oo < 8; ++oo) {
          float vo = bcastf(v, oo);
          if (vo > bv) { bv = vo; bo = oo; }                  // strict > : first-max
        }
        if (lane == 0 && bo == 0) atomicAdd(&ctrl[2 + st], 1);
      }
      __syncthreads();

      float acc[16];
      #pragma unroll
      for (int i = 0; i < 16; ++i) acc[i] = 0.f;

      #pragma unroll 1
      for (int c = 0; c < 8; ++c) {
        if (c < 7) stageA(c + 1, (c + 1) & 1);
        const float* bufc = smem + (c & 1) * 8192;
        #pragma unroll
        for (int kk = 0; kk < 8; kk += 2) {
          const int kloc = wv * 8 + kk;
          float h0 = bufc[kloc * 64 + lane];
          float h1 = bufc[(kloc + 1) * 64 + lane];
          const int kg = c * 128 + kloc;
          f16v w0 = *(const f16v*)(Wx + (size_t)kg * NS + s0);
          f16v w1 = *(const f16v*)(Wx + (size_t)(kg + 1) * NS + s0);
          #pragma unroll
          for (int ss = 0; ss < 16; ++ss) acc[ss] += w0[ss] * h0 + w1[ss] * h1;
        }
        __syncthreads();
      }

      // cross-wave K reduction: red[16 w][16 s][64 b]
      #pragma unroll
      for (int ss = 0; ss < 16; ++ss) smem[wv * 1024 + ss * 64 + lane] = acc[ss];
      __syncthreads();
      {
        const int s = tid >> 6, b = tid & 63;
        float val = bx[s0 + s];
        #pragma unroll
        for (int w = 0; w < 16; ++w) val += smem[w * 1024 + s * 64 + b];
        __syncthreads();
        smem[s * 64 + b] = val;
        __syncthreads();
        if (tid < 64) {
          const int bb = tid;
          float bv = smem[bb]; int bs = 0;
          #pragma unroll
          for (int s2 = 1; s2 < 16; ++s2) {
            float v2 = smem[s2 * 64 + bb];
            if (v2 > bv) { bv = v2; bs = s2; }                // ascending s: first-max
          }
          float2* cp = (float2*)(wsf + OFF_CAND);
          cp[bb * 256 + blk] = make_float2(bv, __int_as_float(s0 + bs));
        }
      }
    }
    gridbar(cnt, ++ep * GRID);

    // ================= PHASE C =================
    // Block (jg: 64 j, bg: 4 b): h_new full K=2048 (hn half + s2a gather half).
    // Redundant per-block ptr-argmax reduction from cand (no extra barrier).
    {
      const int jg = blk & 15, bg = blk >> 4;
      const int j0 = jg << 6, b0 = bg << 2;

      // ptr reduce for b0..b0+3 (every wave redundantly; deterministic)
      int ptrs[4];
      {
        const float2* cp = (const float2*)(wsf + OFF_CAND);
        #pragma unroll
        for (int i = 0; i < 4; ++i) {
          const float2* row = cp + (size_t)(b0 + i) * 256;
          float2 c0 = row[lane];
          float bv = c0.x; int bi = __float_as_int(c0.y);
          #pragma unroll
          for (int q = 1; q < 4; ++q) {
            float2 c = row[q * 64 + lane];
            if (c.x > bv) { bv = c.x; bi = __float_as_int(c.y); }  // ascending idx
          }
          #pragma unroll
          for (int off = 1; off <= 32; off <<= 1) {
            float ov = __shfl_xor(bv, off);
            int   oi = __shfl_xor(bi, off);
            if (ov > bv || (ov == bv && oi < bi)) { bv = ov; bi = oi; }
          }
          ptrs[i] = bi;
        }
      }
      // done flag: any full-stop at a prior step (monotone)
      int done = 0;
      for (int tt = 0; tt < st; ++tt) done |= (ctrl[2 + tt] == NB) ? 1 : 0;

      float2* wl2 = (float2*)smem;       // [2][64 kp][64 j]
      auto stageC = [&](int r, int sel) {
        #pragma unroll
        for (int i = 0; i < 4; ++i) {
          const int id = i * 1024 + tid;
          const int kp = id >> 6, jj = id & 63;
          const float* wp = Wres + (size_t)(r * 128 + 2 * kp) * NH + j0 + jj;
          wl2[sel * 4096 + id] = make_float2(wp[0], wp[NH]);
        }
      };

      stageC(0, 0);
      __syncthreads();

      float a0 = 0.f, a1 = 0.f, a2 = 0.f, a3 = 0.f;
      const int win  = (wv & 12) << 3;   // 32-aligned window base within round
      const int lsel = (wv & 3) << 3;    // position of this wave's 8 k in window

      #pragma unroll 1
      for (int r = 0; r < 16; ++r) {
        if (r < 15) stageC(r + 1, (r + 1) & 1);
        const int kb = r << 7;
        float hv0, hv1, hv2, hv3;
        if (r < 8) {
          const float* hp = hn + kb + win + (lane & 31);
          hv0 = hp[(size_t)(b0 + 0) * NH];
          hv1 = hp[(size_t)(b0 + 1) * NH];
          hv2 = hp[(size_t)(b0 + 2) * NH];
          hv3 = hp[(size_t)(b0 + 3) * NH];
        } else {
          const int ko = kb - NH + win + (lane & 31);
          hv0 = s2a[((size_t)(b0 + 0) * NS + ptrs[0]) * NH + ko];
          hv1 = s2a[((size_t)(b0 + 1) * NS + ptrs[1]) * NH + ko];
          hv2 = s2a[((size_t)(b0 + 2) * NS + ptrs[2]) * NH + ko];
          hv3 = s2a[((size_t)(b0 + 3) * NS + ptrs[3]) * NH + ko];
        }
        const float2* wb = wl2 + (r & 1) * 4096 + (wv * 4) * 64 + lane;
        #pragma unroll
        for (int p = 0; p < 4; ++p) {
          float2 wp2 = wb[p * 64];
          const int k0i = lsel + 2 * p;
          a0 += bcastf(hv0, k0i) * wp2.x; a0 += bcastf(hv0, k0i + 1) * wp2.y;
          a1 += bcastf(hv1, k0i) * wp2.x; a1 += bcastf(hv1, k0i + 1) * wp2.y;
          a2 += bcastf(hv2, k0i) * wp2.x; a2 += bcastf(hv2, k0i + 1) * wp2.y;
          a3 += bcastf(hv3, k0i) * wp2.x; a3 += bcastf(hv3, k0i + 1) * wp2.y;
        }
        __syncthreads();
      }

      // cross-wave reduce: red[16 w][4 b][64 j]
      smem[wv * 256 + 0 * 64 + lane] = a0;
      smem[wv * 256 + 1 * 64 + lane] = a1;
      smem[wv * 256 + 2 * 64 + lane] = a2;
      smem[wv * 256 + 3 * 64 + lane] = a3;
      __syncthreads();

      if (tid < 256) {
        const int bsel = tid >> 6, jloc = tid & 63;
        float v = bres[j0 + jloc];
        #pragma unroll
        for (int w = 0; w < 16; ++w) v += smem[w * 256 + bsel * 64 + jloc];
        const int b = b0 + bsel, j = j0 + jloc;
        float hold = h[(size_t)b * NH + j];
        float hout = done ? hold : v;
        h[(size_t)b * NH + j] = hout;
        if (st < NSTEP - 1) {
          float hnv = hout + 0.01f * noise[(size_t)(st + 1) * (NB * NH) + (size_t)b * NH + j];
          hn[(size_t)b * NH + j]  = hnv;
          hnT[(size_t)j * NB + b] = hnv;
          const float* wr = Wop + (size_t)j * NOPSN;
          float opo[8];
          #pragma unroll
          for (int o = 0; o < 8; ++o) opo[o] = hnv * wr[o];
          #pragma unroll
          for (int off = 1; off <= 32; off <<= 1) {
            #pragma unroll
            for (int o = 0; o < 8; ++o) opo[o] += __shfl_xor(opo[o], off);
          }
          if (lane == 0) {
            float* od = opp + ((size_t)(st + 1) * 16 + jg) * 512 + (size_t)b * 8;
            #pragma unroll
            for (int o = 0; o < 8; ++o) od[o] = opo[o];
          }
        } else {
          out[(size_t)b * NH + j] = hout;
        }
      }
    }
    if (st < NSTEP - 1) gridbar(cnt, ++ep * GRID);
  }
}

extern "C" void kernel_launch(void* const* d_in, const int* in_sizes, int n_in,
                              void* d_out, int out_size, void* d_ws, size_t ws_size,
                              hipStream_t stream) {
  const float* s2a   = (const float*)d_in[0];
  const float* Wres  = (const float*)d_in[1];
  const float* bres  = (const float*)d_in[2];
  const float* Wop   = (const float*)d_in[3];
  const float* bop   = (const float*)d_in[4];
  const float* Wx    = (const float*)d_in[5];
  const float* bx    = (const float*)d_in[6];
  const float* noise = (const float*)d_in[7];
  float* outp = (float*)d_out;
  float* wsf  = (float*)d_ws;   // needs ~1.3 MB
  hipLaunchKernelGGL(sys1_kernel, dim3(GRID), dim3(TPB), 0, stream,
                     s2a, Wres, bres, Wop, bop, Wx, bx, noise, outp, wsf);
}

// Round 3
// 2277.481 us; speedup vs baseline: 1.1836x; 1.0661x over previous
//
#include <hip/hip_runtime.h>
#include <cstdint>
#include <cstddef>

// Problem constants
#define NB    64      // batch
#define NS    4096    // seq len
#define NH    1024    // hidden
#define NOPSN 8
#define NSTEP 10

#define GRID  256
#define TPB   1024    // 16 waves/block, 1 block/CU -> 4 waves/SIMD

// Workspace layout (float offsets). Total ~1.8 MB.
// hn double-buffered by step parity (fixes cross-block write/read race),
// hnT2 = k-pair-interleaved transpose: element (k,b) at [(k>>1)*128 + b*2 + (k&1)]
#define OFF_HN0  0u
#define OFF_HN1  65536u
#define OFF_HT0  131072u
#define OFF_HT1  196608u
#define OFF_H    262144u
#define OFF_CAND 327680u   // cand [64][256] float2 (val, idx-as-float)
#define OFF_OPP  360448u   // oppart [10][16 jg][64 b][8 o]
#define OFF_CTRL 442368u   // int ctrl: [0]=magic [1]=barrier cnt [2..11]=stopcnt[t]
#define MAGIC    0x1357A5E5

typedef float f4v  __attribute__((ext_vector_type(4)));
typedef float f16v __attribute__((ext_vector_type(16)));

__device__ __forceinline__ float bcastf(float v, int l) {
  return __int_as_float(__builtin_amdgcn_readlane(__float_as_int(v), l));
}

// Device-scope grid barrier. 256 blocks x (1024 thr, 64KB LDS, <=128 VGPR)
// -> 1 block/CU on 256 CUs, all resident.
__device__ __forceinline__ void gridbar(int* cnt, int target) {
  __syncthreads();
  if (threadIdx.x == 0) {
    __threadfence();  // release (device scope)
    __hip_atomic_fetch_add(cnt, 1, __ATOMIC_RELAXED, __HIP_MEMORY_SCOPE_AGENT);
    while (__hip_atomic_load(cnt, __ATOMIC_RELAXED, __HIP_MEMORY_SCOPE_AGENT) < target)
      __builtin_amdgcn_s_sleep(1);
    __threadfence();  // acquire
  }
  __syncthreads();
}

__global__ void __launch_bounds__(TPB, 4)
sys1_kernel(const float* __restrict__ s2a,  const float* __restrict__ Wres,
            const float* __restrict__ bres, const float* __restrict__ Wop,
            const float* __restrict__ bop,  const float* __restrict__ Wx,
            const float* __restrict__ bx,   const float* __restrict__ noise,
            float* __restrict__ out,        float* __restrict__ wsf)
{
  __shared__ float smem[16384];   // 64 KB: cross-wave reductions only

  float* __restrict__ h   = wsf + OFF_H;
  float* __restrict__ opp = wsf + OFF_OPP;
  int* ctrl = (int*)(wsf + OFF_CTRL);
  int* cnt  = ctrl + 1;

  const int tid = threadIdx.x;
  const int blk = blockIdx.x;

  // ---- bootstrap: block 0 inits ctrl (ws is poisoned every launch) ----
  if (blk == 0 && tid == 0) {
    #pragma unroll
    for (int i = 1; i < 32; ++i) ctrl[i] = 0;
    __threadfence();
    __hip_atomic_store(&ctrl[0], (int)MAGIC, __ATOMIC_RELEASE, __HIP_MEMORY_SCOPE_AGENT);
  }
  if (tid == 0) {
    while (__hip_atomic_load(&ctrl[0], __ATOMIC_RELAXED, __HIP_MEMORY_SCOPE_AGENT) != (int)MAGIC)
      __builtin_amdgcn_s_sleep(1);
    __threadfence();
  }
  __syncthreads();

  const int lane = tid & 63;
  const int wv   = __builtin_amdgcn_readfirstlane(tid >> 6);   // wave 0..15

  // ---- INIT: hn(0) = 0.01*noise[0] into parity-0 buffers, h=0, oppart[0] ----
  {
    const int jg = blk & 15, bg = blk >> 4;
    if (tid < 256) {
      const int bsel = tid >> 6, jloc = tid & 63;
      const int b = bg * 4 + bsel, j = jg * 64 + jloc;
      float hv = 0.01f * noise[(size_t)b * NH + j];
      (wsf + OFF_HN0)[(size_t)b * NH + j] = hv;
      (wsf + OFF_HT0)[((size_t)(j >> 1)) * 128 + b * 2 + (j & 1)] = hv;
      h[(size_t)b * NH + j] = 0.f;
      const float* wr = Wop + (size_t)j * NOPSN;
      float opo[8];
      #pragma unroll
      for (int o = 0; o < 8; ++o) opo[o] = hv * wr[o];
      #pragma unroll
      for (int off = 1; off <= 32; off <<= 1) {
        #pragma unroll
        for (int o = 0; o < 8; ++o) opo[o] += __shfl_xor(opo[o], off);
      }
      if (lane == 0) {
        float* od = opp + ((size_t)0 * 16 + jg) * 512 + (size_t)b * 8;
        #pragma unroll
        for (int o = 0; o < 8; ++o) od[o] = opo[o];
      }
    }
  }
  int ep = 0;
  gridbar(cnt, ++ep * GRID);

  for (int st = 0; st < NSTEP; ++st) {
    const float* __restrict__ hn_cur  = wsf + ((st & 1) ? OFF_HN1 : OFF_HN0);
    float* __restrict__       hn_nxt  = wsf + ((st & 1) ? OFF_HN0 : OFF_HN1);
    const float* __restrict__ hnT_cur = wsf + ((st & 1) ? OFF_HT1 : OFF_HT0);
    float* __restrict__       hnT_nxt = wsf + ((st & 1) ? OFF_HT0 : OFF_HT1);

    // ================= PHASE A =================
    // Each block: x_logits[16 s cols][64 b], full K=1024. lane = b.
    // Wave owns contiguous 64-k slice. No LDS staging; 2-deep pipeline.
    {
      const int s0 = blk << 4;

      // op-argmax for step st (blocks 0..63)
      if (blk < NB && tid < 64) {
        const float* ob = opp + (size_t)st * 8192 + (size_t)blk * 8;
        const int o = lane & 7, jgb = lane >> 3;              // jgb 0..7
        float v = ob[(size_t)jgb * 512 + o] + ob[(size_t)(jgb + 8) * 512 + o];
        v += __shfl_xor(v, 8);
        v += __shfl_xor(v, 16);
        v += __shfl_xor(v, 32);
        v += bop[o];
        float bv = bcastf(v, 0); int bo = 0;
        #pragma unroll
        for (int oo = 1; oo < 8; ++oo) {
          float vo = bcastf(v, oo);
          if (vo > bv) { bv = vo; bo = oo; }                  // strict > : first-max
        }
        if (lane == 0 && bo == 0) atomicAdd(&ctrl[2 + st], 1);
      }

      const int kbase = wv << 6;                              // 64 k per wave
      const float2* hb = (const float2*)hnT_cur + ((size_t)(kbase >> 1)) * 64 + lane;
      const float*  wb = Wx + (size_t)kbase * NS + s0;        // wave-uniform

      f16v acc;
      #pragma unroll
      for (int ss = 0; ss < 16; ++ss) acc[ss] = 0.f;

      float2 hc = hb[0];
      f16v w0 = *(const f16v*)(wb);
      f16v w1 = *(const f16v*)(wb + NS);
      #pragma unroll 1
      for (int kp = 0; kp < 32; ++kp) {
        float2 hcur = hc;
        f16v w0c = w0, w1c = w1;
        if (kp < 31) {
          hc = hb[(size_t)(kp + 1) * 64];
          const float* wn = wb + (size_t)(2 * kp + 2) * NS;
          w0 = *(const f16v*)(wn);
          w1 = *(const f16v*)(wn + NS);
        }
        #pragma unroll
        for (int ss = 0; ss < 16; ++ss)
          acc[ss] += w0c[ss] * hcur.x + w1c[ss] * hcur.y;
      }

      // cross-wave K reduction: red[16 w][16 s][64 b]
      #pragma unroll
      for (int ss = 0; ss < 16; ++ss) smem[wv * 1024 + ss * 64 + lane] = acc[ss];
      __syncthreads();
      {
        const int s = tid >> 6, b = tid & 63;
        float val = bx[s0 + s];
        #pragma unroll
        for (int w = 0; w < 16; ++w) val += smem[w * 1024 + s * 64 + b];
        __syncthreads();
        smem[s * 64 + b] = val;
        __syncthreads();
        if (tid < 64) {
          const int bb = tid;
          float bv = smem[bb]; int bs = 0;
          #pragma unroll
          for (int s2 = 1; s2 < 16; ++s2) {
            float v2 = smem[s2 * 64 + bb];
            if (v2 > bv) { bv = v2; bs = s2; }                // ascending s: first-max
          }
          float2* cp = (float2*)(wsf + OFF_CAND);
          cp[bb * 256 + blk] = make_float2(bv, __int_as_float(s0 + bs));
        }
      }
    }
    gridbar(cnt, ++ep * GRID);

    // ================= PHASE C =================
    // Block (jg: 64 j, bg: 4 b): h_new full K=2048. lane = j (weights
    // per-lane coalesced), h/s2a wave-uniform float4 loads. 2-deep pipeline.
    {
      const int jg = blk & 15, bg = blk >> 4;
      const int j0 = jg << 6, b0 = bg << 2;

      // ptr reduce for b0..b0+3 (every wave redundantly; deterministic)
      int ptrs[4];
      {
        const float2* cp = (const float2*)(wsf + OFF_CAND);
        #pragma unroll
        for (int i = 0; i < 4; ++i) {
          const float2* row = cp + (size_t)(b0 + i) * 256;
          float2 c0 = row[lane];
          float bv = c0.x; int bi = __float_as_int(c0.y);
          #pragma unroll
          for (int q = 1; q < 4; ++q) {
            float2 c = row[q * 64 + lane];
            if (c.x > bv) { bv = c.x; bi = __float_as_int(c.y); }  // ascending idx
          }
          #pragma unroll
          for (int off = 1; off <= 32; off <<= 1) {
            float ov = __shfl_xor(bv, off);
            int   oi = __shfl_xor(bi, off);
            if (ov > bv || (ov == bv && oi < bi)) { bv = ov; bi = oi; }
          }
          ptrs[i] = __builtin_amdgcn_readfirstlane(bi);
        }
      }
      // done flag: any full-stop at a prior step (monotone)
      int done = 0;
      for (int tt = 0; tt < st; ++tt) done |= (ctrl[2 + tt] == NB) ? 1 : 0;

      const int kb = wv << 7;                                 // 128 k per wave
      const float *p0, *p1, *p2, *p3;                         // wave-uniform bases
      if (wv < 8) {
        p0 = hn_cur + (size_t)(b0 + 0) * NH + kb;
        p1 = hn_cur + (size_t)(b0 + 1) * NH + kb;
        p2 = hn_cur + (size_t)(b0 + 2) * NH + kb;
        p3 = hn_cur + (size_t)(b0 + 3) * NH + kb;
      } else {
        p0 = s2a + ((size_t)(b0 + 0) * NS + ptrs[0]) * NH + (kb - NH);
        p1 = s2a + ((size_t)(b0 + 1) * NS + ptrs[1]) * NH + (kb - NH);
        p2 = s2a + ((size_t)(b0 + 2) * NS + ptrs[2]) * NH + (kb - NH);
        p3 = s2a + ((size_t)(b0 + 3) * NS + ptrs[3]) * NH + (kb - NH);
      }
      const float* wp = Wres + (size_t)kb * NH + j0 + lane;   // per-lane

      float a0 = 0.f, a1 = 0.f, a2 = 0.f, a3 = 0.f;
      f4v h0 = *(const f4v*)p0, h1 = *(const f4v*)p1;
      f4v h2 = *(const f4v*)p2, h3 = *(const f4v*)p3;
      float w0_ = wp[0], w1_ = wp[NH], w2_ = wp[2 * NH], w3_ = wp[3 * NH];

      #pragma unroll 1
      for (int kc = 0; kc < 128; kc += 4) {
        f4v hc0 = h0, hc1 = h1, hc2 = h2, hc3 = h3;
        float wc0 = w0_, wc1 = w1_, wc2 = w2_, wc3 = w3_;
        if (kc + 4 < 128) {
          h0 = *(const f4v*)(p0 + kc + 4);
          h1 = *(const f4v*)(p1 + kc + 4);
          h2 = *(const f4v*)(p2 + kc + 4);
          h3 = *(const f4v*)(p3 + kc + 4);
          const float* wn = wp + (size_t)(kc + 4) * NH;
          w0_ = wn[0]; w1_ = wn[NH]; w2_ = wn[2 * NH]; w3_ = wn[3 * NH];
        }
        a0 += hc0[0] * wc0; a1 += hc1[0] * wc0; a2 += hc2[0] * wc0; a3 += hc3[0] * wc0;
        a0 += hc0[1] * wc1; a1 += hc1[1] * wc1; a2 += hc2[1] * wc1; a3 += hc3[1] * wc1;
        a0 += hc0[2] * wc2; a1 += hc1[2] * wc2; a2 += hc2[2] * wc2; a3 += hc3[2] * wc2;
        a0 += hc0[3] * wc3; a1 += hc1[3] * wc3; a2 += hc2[3] * wc3; a3 += hc3[3] * wc3;
      }

      // cross-wave reduce: red[16 w][4 b][64 j]
      smem[wv * 256 + 0 * 64 + lane] = a0;
      smem[wv * 256 + 1 * 64 + lane] = a1;
      smem[wv * 256 + 2 * 64 + lane] = a2;
      smem[wv * 256 + 3 * 64 + lane] = a3;
      __syncthreads();

      if (tid < 256) {
        const int bsel = tid >> 6, jloc = tid & 63;
        float v = bres[j0 + jloc];
        #pragma unroll
        for (int w = 0; w < 16; ++w) v += smem[w * 256 + bsel * 64 + jloc];
        const int b = b0 + bsel, j = j0 + jloc;
        float hold = h[(size_t)b * NH + j];
        float hout = done ? hold : v;
        h[(size_t)b * NH + j] = hout;
        if (st < NSTEP - 1) {
          float hnv = hout + 0.01f * noise[(size_t)(st + 1) * (NB * NH) + (size_t)b * NH + j];
          hn_nxt[(size_t)b * NH + j] = hnv;
          hnT_nxt[((size_t)(j >> 1)) * 128 + b * 2 + (j & 1)] = hnv;
          const float* wr = Wop + (size_t)j * NOPSN;
          float opo[8];
          #pragma unroll
          for (int o = 0; o < 8; ++o) opo[o] = hnv * wr[o];
          #pragma unroll
          for (int off = 1; off <= 32; off <<= 1) {
            #pragma unroll
            for (int o = 0; o < 8; ++o) opo[o] += __shfl_xor(opo[o], off);
          }
          if (lane == 0) {
            float* od = opp + ((size_t)(st + 1) * 16 + jg) * 512 + (size_t)b * 8;
            #pragma unroll
            for (int o = 0; o < 8; ++o) od[o] = opo[o];
          }
        } else {
          out[(size_t)b * NH + j] = hout;
        }
      }
    }
    if (st < NSTEP - 1) gridbar(cnt, ++ep * GRID);
  }
}

extern "C" void kernel_launch(void* const* d_in, const int* in_sizes, int n_in,
                              void* d_out, int out_size, void* d_ws, size_t ws_size,
                              hipStream_t stream) {
  const float* s2a   = (const float*)d_in[0];
  const float* Wres  = (const float*)d_in[1];
  const float* bres  = (const float*)d_in[2];
  const float* Wop   = (const float*)d_in[3];
  const float* bop   = (const float*)d_in[4];
  const float* Wx    = (const float*)d_in[5];
  const float* bx    = (const float*)d_in[6];
  const float* noise = (const float*)d_in[7];
  float* outp = (float*)d_out;
  float* wsf  = (float*)d_ws;   // needs ~1.8 MB
  hipLaunchKernelGGL(sys1_kernel, dim3(GRID), dim3(TPB), 0, stream,
                     s2a, Wres, bres, Wop, bop, Wx, bx, noise, outp, wsf);
}